// Round 1
// baseline (200.288 us; speedup 1.0000x reference)
//
#include <hip/hip_runtime.h>
#include <math.h>

#define S_ 2
#define N_ 32
#define I_ 4096
#define D_ 128
#define K_ 16
#define C_ 16               // chunks per (s,n) slice
#define P_ (I_ / C_)        // 256 points per block
#define THREADS 256
#define WAVES 4             // THREADS/64
#define KD (K_ * D_)        // 2048 floats per partial
#define GROUP 8             // load-prefetch depth per wave

// Stage 1: each block reduces 256 points of one slice into a [K][D] partial.
// Key change vs previous version: the cluster id k is WAVE-UNIFORM (one point
// per wave per iteration), so the accumulator lives in registers
// (float2 acc[16] = 32 VGPRs/lane) and the update is a scalar-branch switch
// on readfirstlane(k) -> 2 v_max_f32 on statically-indexed regs.
// This removes the per-point LDS read-modify-write dependency chain that was
// throttling global-load issue below the HBM roofline. LDS is only used for
// the index broadcast and the epilogue cross-wave reduction.
__global__ __launch_bounds__(THREADS) void maxpool_main(
    const float* __restrict__ F,      // [S, N, I, D]
    const int*   __restrict__ IDX,    // [S, N*I], value = n*K + local
    float*       __restrict__ WS)     // [S*N*C, K*D] partials (every elt written)
{
    __shared__ float red[WAVES * KD];   // 32 KiB, used only in epilogue
    __shared__ int   kidx[P_];

    const int blk  = blockIdx.x;        // blk = sn*C + c
    const int c    = blk % C_;
    const int sn   = blk / C_;
    const int base = c * P_;
    const int tid  = threadIdx.x;

    kidx[tid] = IDX[sn * I_ + base + tid] & (K_ - 1);
    __syncthreads();

    const int w    = tid >> 6;
    const int lane = tid & 63;
    const float2* src = (const float2*)(F + (size_t)(sn * I_ + base) * D_);

    float2 acc[K_];
    #pragma unroll
    for (int q = 0; q < K_; ++q) acc[q] = make_float2(-INFINITY, -INFINITY);

    #pragma unroll 1
    for (int g = 0; g < P_ / WAVES; g += GROUP) {
        // prefetch group: 8 independent global loads + 8 LDS broadcast reads
        float2 v[GROUP];
        int    kk[GROUP];
        #pragma unroll
        for (int j = 0; j < GROUP; ++j) {
            const int p = (g + j) * WAVES + w;
            kk[j] = kidx[p];                          // LDS broadcast read
            v[j]  = src[(size_t)p * (D_ / 2) + lane]; // coalesced 512B/wave
        }
        // process group: scalar jump on uniform k, register-only update
        #pragma unroll
        for (int j = 0; j < GROUP; ++j) {
            const int k = __builtin_amdgcn_readfirstlane(kk[j]);
            const float2 vv = v[j];
            switch (k) {
#define CASE_(q) case q: acc[q].x = fmaxf(acc[q].x, vv.x); \
                         acc[q].y = fmaxf(acc[q].y, vv.y); break;
                CASE_(0)  CASE_(1)  CASE_(2)  CASE_(3)
                CASE_(4)  CASE_(5)  CASE_(6)  CASE_(7)
                CASE_(8)  CASE_(9)  CASE_(10) CASE_(11)
                CASE_(12) CASE_(13) CASE_(14) CASE_(15)
#undef CASE_
            }
        }
    }

    // epilogue: dump register accs to LDS, reduce the 4 wave-private copies
    float* priv = red + w * KD;
    #pragma unroll
    for (int q = 0; q < K_; ++q)
        ((float2*)(priv + q * D_))[lane] = acc[q];    // 2-way bank alias: free
    __syncthreads();

    float* dst = WS + (size_t)blk * KD;
    #pragma unroll
    for (int e = tid; e < KD; e += THREADS) {
        float m = fmaxf(fmaxf(red[e],           red[e + KD]),
                        fmaxf(red[e + 2 * KD],  red[e + 3 * KD]));
        dst[e] = m;
    }
}

// Stage 2: max over the C=16 chunk-partials per slice -> d_out.
__global__ __launch_bounds__(256) void maxpool_combine(
    const float* __restrict__ WS,     // [S*N, C, K*D]
    float*       __restrict__ OUT)    // [S*N, K*D]
{
    const int i  = blockIdx.x * 256 + threadIdx.x;   // [0, S*N*K*D)
    const int sn = i >> 11;                          // / KD
    const int e  = i & (KD - 1);
    const float* p = WS + ((size_t)sn * C_) * KD + e;
    float m = -INFINITY;
    #pragma unroll
    for (int c = 0; c < C_; ++c) m = fmaxf(m, p[(size_t)c * KD]);
    OUT[i] = m;
}

extern "C" void kernel_launch(void* const* d_in, const int* in_sizes, int n_in,
                              void* d_out, int out_size, void* d_ws, size_t ws_size,
                              hipStream_t stream) {
    const float* F   = (const float*)d_in[0];
    const int*   IDX = (const int*)d_in[1];
    float*       WS  = (float*)d_ws;
    float*       OUT = (float*)d_out;

    maxpool_main<<<S_ * N_ * C_, THREADS, 0, stream>>>(F, IDX, WS);
    maxpool_combine<<<(S_ * N_ * KD) / 256, 256, 0, stream>>>(WS, OUT);
}

// Round 2
// 198.725 us; speedup vs baseline: 1.0079x; 1.0079x over previous
//
#include <hip/hip_runtime.h>
#include <math.h>

#define S_ 2
#define N_ 32
#define I_ 4096
#define D_ 128
#define K_ 16
#define THREADS 256
#define WAVES 4             // THREADS/64
#define GROUP 8             // load-prefetch depth per wave
#define MAXPTS 1024         // point-list capacity; E[n]=256, sd=15.5 -> huge margin

// Fused single kernel: block = one output segment (sn, k).
//  Phase 1: ballot-compact the positions of this block's cluster from the
//           16 KB idx slice into an LDS list (each point matches exactly one
//           k, so F is still read exactly once across the grid).
//  Phase 2: stream the ~256 matching rows (512 B each, coalesced float2/lane)
//           with 8-deep prefetch into a single register accumulator.
//  Phase 3: 4-wave LDS reduce, write 512 B directly to OUT.
// Deletes: workspace round-trip (16.8 MiB), combine kernel, big LDS epilogue.
__global__ __launch_bounds__(THREADS) void maxpool_fused(
    const float* __restrict__ F,      // [S, N, I, D]
    const int*   __restrict__ IDX,    // [S, N*I], value = n*K + local
    float*       __restrict__ OUT)    // [S, N, K, D]
{
    __shared__ int    plist[MAXPTS];
    __shared__ int    cnt;
    __shared__ float2 red[WAVES][64];

    const int blk  = blockIdx.x;      // blk = sn*K + k
    const int sn   = blk >> 4;
    const int k    = blk & (K_ - 1);
    const int tid  = threadIdx.x;
    const int w    = tid >> 6;
    const int lane = tid & 63;

    if (tid == 0) cnt = 0;
    __syncthreads();

    // ---- Phase 1: compaction (16 rounds, coalesced idx reads) ----
    const int* idxs = IDX + sn * I_;
    for (int r = 0; r < I_ / THREADS; ++r) {
        const int pos = r * THREADS + tid;
        const bool m  = (idxs[pos] & (K_ - 1)) == k;   // local id = idx mod K
        const unsigned long long bal = __ballot(m);
        int base = 0;
        if (lane == 0) base = atomicAdd(&cnt, __popcll(bal));
        base = __shfl(base, 0);
        if (m) {
            const int off = __popcll(bal & ((1ull << lane) - 1ull));
            plist[base + off] = pos;
        }
    }
    __syncthreads();
    const int nm = cnt;

    // ---- Phase 2: stream matching rows, register accumulate ----
    const float2* src = (const float2*)(F + (size_t)sn * I_ * D_);
    float2 acc = make_float2(-INFINITY, -INFINITY);

    int j = w;
    while (j + (GROUP - 1) * WAVES < nm) {
        int    pp[GROUP];
        float2 v[GROUP];
        #pragma unroll
        for (int u = 0; u < GROUP; ++u) pp[u] = plist[j + u * WAVES];
        #pragma unroll
        for (int u = 0; u < GROUP; ++u)
            v[u] = src[(size_t)pp[u] * (D_ / 2) + lane];   // 512 B/wave, coalesced
        #pragma unroll
        for (int u = 0; u < GROUP; ++u) {
            acc.x = fmaxf(acc.x, v[u].x);
            acc.y = fmaxf(acc.y, v[u].y);
        }
        j += GROUP * WAVES;
    }
    for (; j < nm; j += WAVES) {
        const float2 v = src[(size_t)plist[j] * (D_ / 2) + lane];
        acc.x = fmaxf(acc.x, v.x);
        acc.y = fmaxf(acc.y, v.y);
    }

    // ---- Phase 3: cross-wave reduce + direct output write ----
    red[w][lane] = acc;
    __syncthreads();
    if (tid < 64) {
        const float2 a = red[0][tid], b = red[1][tid];
        const float2 c = red[2][tid], d = red[3][tid];
        float2 m;
        m.x = fmaxf(fmaxf(a.x, b.x), fmaxf(c.x, d.x));
        m.y = fmaxf(fmaxf(a.y, b.y), fmaxf(c.y, d.y));
        ((float2*)(OUT + (size_t)blk * D_))[tid] = m;      // 512 B, coalesced
    }
}

extern "C" void kernel_launch(void* const* d_in, const int* in_sizes, int n_in,
                              void* d_out, int out_size, void* d_ws, size_t ws_size,
                              hipStream_t stream) {
    const float* F   = (const float*)d_in[0];
    const int*   IDX = (const int*)d_in[1];
    float*       OUT = (float*)d_out;
    (void)d_ws; (void)ws_size;

    maxpool_fused<<<S_ * N_ * K_, THREADS, 0, stream>>>(F, IDX, OUT);
}